// Round 9
// baseline (316.996 us; speedup 1.0000x reference)
//
#include <hip/hip_runtime.h>

#define LOG2E 1.44269504088896340736f
#define LN2   0.69314718055994530942f

typedef short bf8 __attribute__((ext_vector_type(8)));   // 8 bf16 (A/B frag)
typedef float f4  __attribute__((ext_vector_type(4)));   // 4 f32  (C/D frag)
typedef float v2f __attribute__((ext_vector_type(2)));   // packed f32 pair

static __device__ __forceinline__ unsigned short f2bf_rne(float f) {
    unsigned u = __float_as_uint(f);
    u += 0x7FFFu + ((u >> 16) & 1u);
    return (unsigned short)(u >> 16);
}
// pack two f32 -> two bf16 (truncation; verified absmax 0.0 since R6)
static __device__ __forceinline__ unsigned pack_bf_trunc(float lo, float hi) {
    return __builtin_amdgcn_perm(__float_as_uint(hi), __float_as_uint(lo), 0x07060302u);
}

// ============================================================================
// Kernel 1: per-(batch, chunk-pair) operator products — TWO independent
// chunks per wave, interleaved in one straight-line step body so stream B's
// MFMAs fill stream A's LDS-wait shadow (and vice versa).
//   Op_t = mask_t ? D_t * M^T : I,  D_t = diag(exp(em_t)*2^-7), M = exp(tr)
// LDS: per-stream swizzled P^T (16B-chunk index ^= row&7) — both the b128
// B-frag reads and b64 C-writes are at the LDS bank structural minimum
// (R8 bank arithmetic; residual counter is free 2-way aliasing).
// Masks are ~98% true: compute unconditionally, predicate only writebacks.
// ============================================================================
template <int CH>
__global__ __attribute__((amdgpu_flat_work_group_size(64, 64), amdgpu_waves_per_eu(1, 2)))
void crf_scan2(const int* __restrict__ yg, const float* __restrict__ em,
               const float* __restrict__ tr, unsigned short* __restrict__ Pg)
{
    constexpr int T = 1024, STEPS = T / CH;
    const int cx = blockIdx.x, b = blockIdx.y;
    const int cA = 2 * cx, cB = 2 * cx + 1;
    const int lane = threadIdx.x, nl = lane & 15, q = lane >> 4;
    const int swz = lane & 7;                 // row&7 for this lane's rows

    __shared__ __align__(16) unsigned short pA[64 * 64], pB[64 * 64];
    __shared__ __align__(16) float dA[64], dB[64];

    // ---- P = I (single wave => DS pipe in-order; no barriers needed) ----
    #pragma unroll
    for (int r = 0; r < 8; ++r) {
        uint4 z; z.x = z.y = z.z = z.w = 0u;
        *(uint4*)&pA[lane * 64 + r * 8] = z;
        *(uint4*)&pB[lane * 64 + r * 8] = z;
    }
    const int diag = lane * 64 + (((lane >> 3) ^ swz) << 3) + (lane & 7);
    pA[diag] = 0x3F80;  pB[diag] = 0x3F80;    // bf16 1.0

    // ---- A-fragments of M^T (constant, shared by both streams) ----
    bf8 afr[4][2];
    #pragma unroll
    for (int mt = 0; mt < 4; ++mt)
        #pragma unroll
        for (int kt = 0; kt < 2; ++kt) {
            bf8 v;
            #pragma unroll
            for (int j = 0; j < 8; ++j) {
                const int k = 32 * kt + 8 * q + j, m = 16 * mt + nl;
                v[j] = (short)f2bf_rne(exp2f(tr[k * 64 + m] * LOG2E));
            }
            afr[mt][kt] = v;
        }

    const int t0A = 1 + STEPS * cA, t0B = 1 + STEPS * cB;
    const int nsA = (cA == CH - 1) ? STEPS - 1 : STEPS;
    const int nsB = (cB == CH - 1) ? STEPS - 1 : STEPS;
    const float* emb = em + (size_t)b * T * 64;

    int tlA = t0A + lane; if (tlA > T - 1) tlA = T - 1;
    int tlB = t0B + lane; if (tlB > T - 1) tlB = T - 1;
    const unsigned long long mskA = __ballot(lane < nsA && yg[b * T + tlA] != 0);
    const unsigned long long mskB = __ballot(lane < nsB && yg[b * T + tlB] != 0);

    const f4 zf4 = {0.f, 0.f, 0.f, 0.f};

    float ldcA = emb[t0A * 64 + lane];
    float ldcB = emb[t0B * 64 + lane];

    for (int s = 0; s < STEPS; ++s) {
        int tnA = t0A + s + 1; if (tnA > T - 1) tnA = T - 1;
        int tnB = t0B + s + 1; if (tnB > T - 1) tnB = T - 1;
        const float ldnA = emb[tnA * 64 + lane];
        const float ldnB = emb[tnB * 64 + lane];

        dA[lane] = exp2f(ldcA * LOG2E - 7.0f);
        dB[lane] = exp2f(ldcB * LOG2E - 7.0f);

        // ---- B-fragments for both streams (16 x ds_read_b128) ----
        bf8 bA[2][4], bB[2][4];
        #pragma unroll
        for (int kt = 0; kt < 2; ++kt)
            #pragma unroll
            for (int nt = 0; nt < 4; ++nt) {
                const int off = (16 * nt + nl) * 64 + (((4 * kt + q) ^ swz) << 3);
                bA[kt][nt] = *(const bf8*)&pA[off];
                bB[kt][nt] = *(const bf8*)&pB[off];
            }
        // ---- per-row d vectors (rows 16mt+4q+0..3) ----
        v2f dA01[4], dA23[4], dB01[4], dB23[4];
        #pragma unroll
        for (int mt = 0; mt < 4; ++mt) {
            const f4 va = *(const f4*)&dA[16 * mt + 4 * q];
            const f4 vb = *(const f4*)&dB[16 * mt + 4 * q];
            dA01[mt] = (v2f){va[0], va[1]};  dA23[mt] = (v2f){va[2], va[3]};
            dB01[mt] = (v2f){vb[0], vb[1]};  dB23[mt] = (v2f){vb[2], vb[3]};
        }

        // ---- compute both streams' C tiles (unconditional) ----
        uint2 wA[4][4], wB[4][4];
        #pragma unroll
        for (int mt = 0; mt < 4; ++mt)
            #pragma unroll
            for (int nt = 0; nt < 4; ++nt) {
                f4 accA = __builtin_amdgcn_mfma_f32_16x16x32_bf16(
                              afr[mt][0], bA[0][nt], zf4, 0, 0, 0);
                f4 accB = __builtin_amdgcn_mfma_f32_16x16x32_bf16(
                              afr[mt][0], bB[0][nt], zf4, 0, 0, 0);
                accA = __builtin_amdgcn_mfma_f32_16x16x32_bf16(
                              afr[mt][1], bA[1][nt], accA, 0, 0, 0);
                accB = __builtin_amdgcn_mfma_f32_16x16x32_bf16(
                              afr[mt][1], bB[1][nt], accB, 0, 0, 0);
                const v2f loA = (v2f){accA[0], accA[1]} * dA01[mt];
                const v2f hiA = (v2f){accA[2], accA[3]} * dA23[mt];
                const v2f loB = (v2f){accB[0], accB[1]} * dB01[mt];
                const v2f hiB = (v2f){accB[2], accB[3]} * dB23[mt];
                wA[mt][nt].x = pack_bf_trunc(loA.x, loA.y);
                wA[mt][nt].y = pack_bf_trunc(hiA.x, hiA.y);
                wB[mt][nt].x = pack_bf_trunc(loB.x, loB.y);
                wB[mt][nt].y = pack_bf_trunc(hiB.x, hiB.y);
            }

        // ---- predicated writebacks (wave-uniform; stores only) ----
        if ((mskA >> s) & 1ull) {
            #pragma unroll
            for (int mt = 0; mt < 4; ++mt)
                #pragma unroll
                for (int nt = 0; nt < 4; ++nt)
                    *(uint2*)&pA[(16 * nt + nl) * 64 +
                                 (((2 * mt + (q >> 1)) ^ swz) << 3) +
                                 ((q & 1) << 2)] = wA[mt][nt];
        }
        if ((mskB >> s) & 1ull) {
            #pragma unroll
            for (int mt = 0; mt < 4; ++mt)
                #pragma unroll
                for (int nt = 0; nt < 4; ++nt)
                    *(uint2*)&pB[(16 * nt + nl) * 64 +
                                 (((2 * mt + (q >> 1)) ^ swz) << 3) +
                                 ((q & 1) << 2)] = wB[mt][nt];
        }
        ldcA = ldnA;  ldcB = ldnB;
    }

    // ---- de-swizzled dumps: Pg[(b*CH+c)*4096 + n*64 + k] = P_c[k][n] ----
    unsigned short* pgA = Pg + ((size_t)(b * CH + cA) << 12);
    unsigned short* pgB = Pg + ((size_t)(b * CH + cB) << 12);
    #pragma unroll
    for (int r = 0; r < 8; ++r) {
        *(uint4*)(pgA + lane * 64 + r * 8) =
            *(const uint4*)&pA[lane * 64 + ((r ^ swz) << 3)];
        *(uint4*)(pgB + lane * 64 + r * 8) =
            *(const uint4*)&pB[lane * 64 + ((r ^ swz) << 3)];
    }
}

// ============================================================================
// Kernel 2: per-batch combine — v = P_{CH-1} ... P_0 * exp(e0 - M0), plus
// gather scores, logZ, final -mean. 256 waves; rows double-buffered in regs.
// ============================================================================
template <int CH>
__global__ __attribute__((amdgpu_flat_work_group_size(64, 64), amdgpu_waves_per_eu(1, 1)))
void crf_combine(const int* __restrict__ yg, const float* __restrict__ em,
                 const float* __restrict__ tr, const unsigned short* __restrict__ Pg,
                 float* __restrict__ out)
{
    constexpr int T = 1024;
    const int b = blockIdx.x, j = threadIdx.x;
    __shared__ __align__(16) float v_sh[64];

    const float e0 = em[(size_t)b * T * 64 + j];
    float M0 = e0;
    #pragma unroll
    for (int o = 32; o > 0; o >>= 1) M0 = fmaxf(M0, __shfl_xor(M0, o, 64));
    float v = exp2f((e0 - M0) * LOG2E);
    float L = M0;

    // ---- scores + unmasked-step count (lane-strided over t) ----
    const int* yb = yg + b * T;
    int cnt = 0; float ep = 0.f, tp = 0.f;
    for (int t = 1 + j; t < T; t += 64) {
        const int yt = yb[t];
        if (yt != 0) {
            ++cnt;
            tp += tr[yb[t - 1] * 64 + yt];
            ep += em[((size_t)b * T + t) * 64 + yt];
        }
    }
    if (j == 0) {
        const int y0 = yb[0];
        if (y0 != 0) ep += em[(size_t)b * T * 64 + y0];
    }

    // ---- apply CH chunk operators (rows double-buffered in registers) ----
    const unsigned short* pgb = Pg + ((size_t)b * CH << 12) + j * 64;
    uint4 cur[8];
    {
        const uint4* p = (const uint4*)pgb;
        #pragma unroll
        for (int r = 0; r < 8; ++r) cur[r] = p[r];
    }
    for (int c = 0; c < CH; ++c) {
        uint4 nxt[8];
        if (c < CH - 1) {
            const uint4* p = (const uint4*)(pgb + ((size_t)(c + 1) << 12));
            #pragma unroll
            for (int r = 0; r < 8; ++r) nxt[r] = p[r];
        }
        v_sh[j] = v;                       // single wave: in-order DS pipe
        float s0 = 0.f, s1 = 0.f, s2 = 0.f, s3 = 0.f;
        #pragma unroll
        for (int r = 0; r < 8; ++r) {
            const uint4 qq = cur[r];
            const float* vp = &v_sh[r * 8];
            s0 = fmaf(__uint_as_float(qq.x << 16),         vp[0], s0);
            s1 = fmaf(__uint_as_float(qq.x & 0xFFFF0000u), vp[1], s1);
            s2 = fmaf(__uint_as_float(qq.y << 16),         vp[2], s2);
            s3 = fmaf(__uint_as_float(qq.y & 0xFFFF0000u), vp[3], s3);
            s0 = fmaf(__uint_as_float(qq.z << 16),         vp[4], s0);
            s1 = fmaf(__uint_as_float(qq.z & 0xFFFF0000u), vp[5], s1);
            s2 = fmaf(__uint_as_float(qq.w << 16),         vp[6], s2);
            s3 = fmaf(__uint_as_float(qq.w & 0xFFFF0000u), vp[7], s3);
        }
        float s = (s0 + s1) + (s2 + s3);
        // exact-pow2 re-centering (wave-uniform), fold into L
        const unsigned sb = (unsigned)__builtin_amdgcn_readlane((int)__float_as_uint(s), 0);
        const int ef = (int)((sb >> 23) & 0xFF);
        if (ef > 0 && ef < 255 && ef != 127) {
            const int E = ef - 127;
            s *= __uint_as_float((unsigned)(127 - E) << 23);
            L += (float)E * LN2;
        }
        v = s;
        if (c < CH - 1) {
            #pragma unroll
            for (int r = 0; r < 8; ++r) cur[r] = nxt[r];
        }
    }

    // ---- reduce & finalize ----
    float vs = v, eps = ep, tps = tp; int cs = cnt;
    #pragma unroll
    for (int o = 32; o > 0; o >>= 1) {
        vs  += __shfl_xor(vs, o, 64);
        eps += __shfl_xor(eps, o, 64);
        tps += __shfl_xor(tps, o, 64);
        cs  += __shfl_xor(cs, o, 64);
    }
    if (j == 0) {
        const float logz = L + 7.0f * LN2 * (float)cs + __log2f(vs) * LN2;
        const float ll = eps + tps - logz;
        atomicAdd(out, ll * (-1.0f / 256.0f));
    }
}

extern "C" void kernel_launch(void* const* d_in, const int* in_sizes, int n_in,
                              void* d_out, int out_size, void* d_ws, size_t ws_size,
                              hipStream_t stream) {
    const int*   y  = (const int*)d_in[0];
    const float* em = (const float*)d_in[1];
    const float* tr = (const float*)d_in[2];
    float* out = (float*)d_out;
    unsigned short* Pg = (unsigned short*)d_ws;

    hipMemsetAsync(out, 0, sizeof(float), stream);
    const size_t need32 = (size_t)256 * 32 * 4096 * 2;   // 64 MB
    if (ws_size >= need32) {
        crf_scan2<32><<<dim3(16, 256), dim3(64), 0, stream>>>(y, em, tr, Pg);
        crf_combine<32><<<dim3(256), dim3(64), 0, stream>>>(y, em, tr, Pg, out);
    } else {                                             // 32 MB fallback
        crf_scan2<16><<<dim3(8, 256), dim3(64), 0, stream>>>(y, em, tr, Pg);
        crf_combine<16><<<dim3(256), dim3(64), 0, stream>>>(y, em, tr, Pg, out);
    }
}